// Round 14
// baseline (118.413 us; speedup 1.0000x reference)
//
#include <hip/hip_runtime.h>
#include <hip/hip_bf16.h>

typedef _Float16 f16x8 __attribute__((ext_vector_type(8)));
typedef float f32x4 __attribute__((ext_vector_type(4)));
typedef float f32x16 __attribute__((ext_vector_type(16)));

#define T_DIM 2048
#define H_DIM 2048
#define N_HEADS 16
#define DH 128
#define KBLK 50
#define NBLK 41
#define NEGV (-1.0e9f)
#define QSCALE 0.08838834764831845f  // 128^-0.5

__device__ __forceinline__ void gl_lds16(const void* g, void* l) {
    __builtin_amdgcn_global_load_lds(
        (const __attribute__((address_space(1))) void*)g,
        (__attribute__((address_space(3))) void*)l, 16, 0, 0);
}

// ---- prep: z<3 -> transpose Wq/Wk/Wv fp32->fp16; z==3 -> convert x fp32->fp16 ----
__global__ __launch_bounds__(256) void prep_kernel(const float* __restrict__ x,
                                                   const float* __restrict__ Wq,
                                                   const float* __restrict__ Wk,
                                                   const float* __restrict__ Wv,
                                                   _Float16* __restrict__ xb,
                                                   _Float16* __restrict__ WT) {
    __shared__ float tile[32][33];
    int z = blockIdx.z;
    int tx = threadIdx.x, ty = threadIdx.y;  // 32 x 8
    if (z == 3) {
        if (blockIdx.y >= 32) return;
        int flat = blockIdx.y * 64 + blockIdx.x;
        int i = (flat * 256 + ty * 32 + tx) * 8;
        float4 a = *(const float4*)&x[i];
        float4 b = *(const float4*)&x[i + 4];
        f16x8 o = {(_Float16)a.x, (_Float16)a.y, (_Float16)a.z, (_Float16)a.w,
                   (_Float16)b.x, (_Float16)b.y, (_Float16)b.z, (_Float16)b.w};
        *(f16x8*)&xb[i] = o;
        return;
    }
    const float* src = (z == 0) ? Wq : (z == 1) ? Wk : Wv;
    _Float16* dst = WT + (size_t)z * T_DIM * H_DIM;
    int bx = blockIdx.x * 32, by = blockIdx.y * 32;
#pragma unroll
    for (int i = 0; i < 4; i++)
        tile[ty + i * 8][tx] = src[(size_t)(by + ty + i * 8) * H_DIM + bx + tx];
    __syncthreads();
#pragma unroll
    for (int i = 0; i < 4; i++)
        dst[(size_t)(bx + ty + i * 8) * H_DIM + by + tx] = (_Float16)tile[tx][ty + i * 8];
}

// =============== QKV projection: 128x192 tile, 32x32x16 MFMA, 3-phase, 512 blocks ========
// Wave tile 64x96 = 2Mfrag x 3Nfrag of 32x32; acc 6 x f32x16. BK=64 -> 4 k-slices of 16.
// Phases: ph0 reads a(all)+b[nf0], MFMA nf0 (8); ph1 reads b[nf1],b[nf2], MFMA nf1 (8);
// ph2 MFMA nf2 (8, regs only). Stage: ph0 B012(t+1), ph1 B345(t+1), ph2 A0123(t+2).
// Ledger: at (t,ph2) outstanding = A(t+1)4 + B(t+1)6 + A(t+2)4 = 14; vmcnt(4) drains
// tile t+1 exactly; A(t+2) overwrites A-region of buf[t&1] only after ph0-end barrier
// (all tile-t A-reads drained per-wave by ph0 lgkmcnt(0), block-wide by its barrier).
// Tail vmcnt(0) at t=NT-2. A-frag layout: row=lane&31, k=(lane>>5)*8+j (16B read).
// C/D layout (m74/m101): col=lane&31, row=(reg&3)+8*(reg>>2)+4*(lane>>5).
__global__ __launch_bounds__(256, 2) void qkv_kernel(const _Float16* __restrict__ A,
                                                     const _Float16* __restrict__ BT,
                                                     _Float16* __restrict__ qkv) {
    const int K = 2048, NT = 32;
    __shared__ _Float16 smem[40960];  // 80KB: A dbuf 2x8192 | B dbuf 2x12288
    _Float16* sA0 = smem;
    _Float16* sA1 = smem + 8192;
    _Float16* sB0 = smem + 16384;
    _Float16* sB1 = smem + 28672;

    int tid = threadIdx.x;
    int lane = tid & 63, wave = tid >> 6;
    int wm = wave >> 1, wn = wave & 1;  // 2M x 2N, wave tile 64x96
    int cb32 = lane & 31, hi2 = lane >> 5;

    int bid = blockIdx.x;
    int by = bid >> 5, bx = bid & 31;
    int bm = by * 128, bn = bx * 192;

    f32x16 acc[2][3];
#pragma unroll
    for (int m = 0; m < 2; m++)
#pragma unroll
        for (int n = 0; n < 3; n++)
#pragma unroll
            for (int r = 0; r < 16; r++) acc[m][n][r] = 0.f;

    int rp = tid >> 3, cc = tid & 7;  // 32 rows/unit, 8 chunks/row
    int scol = ((cc ^ (rp & 7)) << 3);

    auto stageA = [&](int t, int u) {
        gl_lds16(A + (size_t)(bm + u * 32 + rp) * K + (t << 6) + scol,
                 ((t & 1) ? sA1 : sA0) + u * 2048 + tid * 8);
    };
    auto stageB = [&](int t, int u) {
        gl_lds16(BT + (size_t)(bn + u * 32 + rp) * K + (t << 6) + scol,
                 ((t & 1) ? sB1 : sB0) + u * 2048 + tid * 8);
    };

    f16x8 a[2][4], b2[4];

    // prologue: tile0 all units + A(1); vmcnt(4) -> tile0 landed (A(1) still in flight)
    stageA(0, 0); stageA(0, 1); stageA(0, 2); stageA(0, 3);
    stageB(0, 0); stageB(0, 1); stageB(0, 2); stageB(0, 3); stageB(0, 4); stageB(0, 5);
    stageA(1, 0); stageA(1, 1); stageA(1, 2); stageA(1, 3);
    asm volatile("s_waitcnt vmcnt(4)" ::: "memory");
    __builtin_amdgcn_s_barrier();

    for (int t = 0; t < NT; t++) {
        int buf = t & 1;
        const char* bA = (const char*)(buf ? sA1 : sA0);
        const char* bB = (const char*)(buf ? sB1 : sB0);

        // ---- ph0: read a(8) + b[nf0](4); stage B012(t+1); MFMA nf0 (8) ----
        f16x8 b0[4];
#pragma unroll
        for (int mf = 0; mf < 2; mf++) {
            int ra = wm * 64 + mf * 32 + cb32;
#pragma unroll
            for (int ks = 0; ks < 4; ks++)
                a[mf][ks] = *(const f16x8*)(bA + (ra << 7) +
                                            ((ks * 32 + hi2 * 16) ^ ((ra & 7) << 4)));
        }
        {
            int rb = wn * 96 + cb32;
#pragma unroll
            for (int ks = 0; ks < 4; ks++)
                b0[ks] = *(const f16x8*)(bB + (rb << 7) +
                                         ((ks * 32 + hi2 * 16) ^ ((rb & 7) << 4)));
        }
        if (t + 1 < NT) { stageB(t + 1, 0); stageB(t + 1, 1); stageB(t + 1, 2); }
        __builtin_amdgcn_s_barrier();
        asm volatile("s_waitcnt lgkmcnt(0)" ::: "memory");
        __builtin_amdgcn_s_setprio(1);
#pragma unroll
        for (int mf = 0; mf < 2; mf++)
#pragma unroll
            for (int ks = 0; ks < 4; ks++)
                acc[mf][0] = __builtin_amdgcn_mfma_f32_32x32x16_f16(a[mf][ks], b0[ks], acc[mf][0], 0, 0, 0);
        __builtin_amdgcn_s_setprio(0);
        __builtin_amdgcn_s_barrier();

        // ---- ph1: read b[nf1](4) + b[nf2](4); stage B345(t+1); MFMA nf1 (8) ----
        f16x8 b1[4];
        {
            int rb1 = wn * 96 + 32 + cb32;
            int rb2 = wn * 96 + 64 + cb32;
#pragma unroll
            for (int ks = 0; ks < 4; ks++) {
                b1[ks] = *(const f16x8*)(bB + (rb1 << 7) +
                                         ((ks * 32 + hi2 * 16) ^ ((rb1 & 7) << 4)));
                b2[ks] = *(const f16x8*)(bB + (rb2 << 7) +
                                         ((ks * 32 + hi2 * 16) ^ ((rb2 & 7) << 4)));
            }
        }
        if (t + 1 < NT) { stageB(t + 1, 3); stageB(t + 1, 4); stageB(t + 1, 5); }
        __builtin_amdgcn_s_barrier();
        asm volatile("s_waitcnt lgkmcnt(0)" ::: "memory");
        __builtin_amdgcn_s_setprio(1);
#pragma unroll
        for (int mf = 0; mf < 2; mf++)
#pragma unroll
            for (int ks = 0; ks < 4; ks++)
                acc[mf][1] = __builtin_amdgcn_mfma_f32_32x32x16_f16(a[mf][ks], b1[ks], acc[mf][1], 0, 0, 0);
        __builtin_amdgcn_s_setprio(0);
        __builtin_amdgcn_s_barrier();

        // ---- ph2: stage A0123(t+2); vmcnt confirms tile t+1; MFMA nf2 (8, regs) ----
        if (t + 2 < NT) { stageA(t + 2, 0); stageA(t + 2, 1); stageA(t + 2, 2); stageA(t + 2, 3); }
        if (t < NT - 2)
            asm volatile("s_waitcnt vmcnt(4)" ::: "memory");
        else if (t == NT - 2)
            asm volatile("s_waitcnt vmcnt(0)" ::: "memory");
        __builtin_amdgcn_s_barrier();
        __builtin_amdgcn_s_setprio(1);
#pragma unroll
        for (int mf = 0; mf < 2; mf++)
#pragma unroll
            for (int ks = 0; ks < 4; ks++)
                acc[mf][2] = __builtin_amdgcn_mfma_f32_32x32x16_f16(a[mf][ks], b2[ks], acc[mf][2], 0, 0, 0);
        __builtin_amdgcn_s_setprio(0);
        __builtin_amdgcn_s_barrier();
    }

    // epilogue: single-pass LDS repack [128][200] -> coalesced uint4 scatter
#pragma unroll
    for (int mf = 0; mf < 2; mf++)
#pragma unroll
        for (int nf = 0; nf < 3; nf++) {
            int col = wn * 96 + nf * 32 + cb32;
            float sc = ((bn + col) >> 11) == 0 ? QSCALE : 1.0f;
#pragma unroll
            for (int reg = 0; reg < 16; reg++) {
                int row = wm * 64 + mf * 32 + (reg & 3) + 8 * (reg >> 2) + 4 * hi2;
                smem[row * 200 + col] = (_Float16)(acc[mf][nf][reg] * sc);
            }
        }
    __builtin_amdgcn_s_barrier();
#pragma unroll
    for (int it = 0; it < 12; it++) {
        int c = it * 256 + tid;  // 3072 chunks = 128 rows x 24
        int row = c / 24, col8 = c - row * 24;
        int gm = bm + row;
        int gn = bn + col8 * 8;
        int tensor = gn >> 11;
        int ef = gn & 2047;
        int e = ef >> 7, f0 = ef & 127;
        uint4 v = *(const uint4*)&smem[row * 200 + col8 * 8];
        *(uint4*)(qkv + (size_t)tensor * (T_DIM * H_DIM) + (size_t)e * (T_DIM * DH) +
                  (size_t)gm * DH + f0) = v;
    }
}

// =============== out-proj: 128x64 tile, BK=64, triple-buffer 72KB, 2 blocks/CU ==========
__global__ __launch_bounds__(256, 2) void oproj_kernel(const _Float16* __restrict__ A,
                                                       const _Float16* __restrict__ BT,
                                                       float* __restrict__ out) {
    const int K = 2048, NT = 32;
    __shared__ _Float16 smem[36864];  // 72KB: 3 bufs x (A 8192 | B 4096) f16

    int tid = threadIdx.x;
    int lane = tid & 63, wave = tid >> 6;
    int wm = wave >> 1, wn = wave & 1;  // 2M x 2N, wave tile 64x32
    int cb = lane & 15, hi = lane >> 4;

    int bid = blockIdx.x;
    int by = bid >> 5, bx = bid & 31;
    int bm = by * 128, bn = bx * 64;

    f32x4 acc[4][2];
#pragma unroll
    for (int m = 0; m < 4; m++)
#pragma unroll
        for (int n = 0; n < 2; n++) acc[m][n] = (f32x4){0.f, 0.f, 0.f, 0.f};

    int rp = tid >> 3, cc = tid & 7;
    int scol = ((cc ^ (rp & 7)) << 3);

    auto bufp = [&](int t) { return smem + (t % 3) * 12288; };
    auto stageA = [&](int t, int u) {
        gl_lds16(A + (size_t)(bm + u * 32 + rp) * K + (t << 6) + scol,
                 bufp(t) + u * 2048 + tid * 8);
    };
    auto stageB = [&](int t, int u) {
        gl_lds16(BT + (size_t)(bn + u * 32 + rp) * K + (t << 6) + scol,
                 bufp(t) + 8192 + u * 2048 + tid * 8);
    };

    f16x8 a[4][2], b0[2], b1[2];

    stageA(0, 0); stageA(0, 1); stageA(0, 2); stageA(0, 3); stageB(0, 0); stageB(0, 1);
    stageA(1, 0); stageA(1, 1); stageA(1, 2); stageA(1, 3); stageB(1, 0); stageB(1, 1);
    asm volatile("s_waitcnt vmcnt(6)" ::: "memory");
    __builtin_amdgcn_s_barrier();

    for (int t = 0; t < NT; t++) {
        const char* bA = (const char*)bufp(t);
        const char* bB = bA + 16384;  // 8192 f16
        // ---- ph0: read a(8) + b0(2); stage A(t+2) x4; MFMA a x b0 ----
#pragma unroll
        for (int mf = 0; mf < 4; mf++) {
            int ra = wm * 64 + mf * 16 + cb;
#pragma unroll
            for (int ks = 0; ks < 2; ks++)
                a[mf][ks] = *(const f16x8*)(bA + (ra << 7) +
                                            ((ks * 64 + hi * 16) ^ ((ra & 7) << 4)));
        }
        {
            int rb = wn * 32 + cb;
#pragma unroll
            for (int ks = 0; ks < 2; ks++)
                b0[ks] = *(const f16x8*)(bB + (rb << 7) +
                                         ((ks * 64 + hi * 16) ^ ((rb & 7) << 4)));
        }
        if (t + 2 < NT) { stageA(t + 2, 0); stageA(t + 2, 1); stageA(t + 2, 2); stageA(t + 2, 3); }
        __builtin_amdgcn_s_barrier();
        asm volatile("s_waitcnt lgkmcnt(0)" ::: "memory");
        __builtin_amdgcn_s_setprio(1);
#pragma unroll
        for (int mf = 0; mf < 4; mf++)
#pragma unroll
            for (int ks = 0; ks < 2; ks++)
                acc[mf][0] = __builtin_amdgcn_mfma_f32_16x16x32_f16(a[mf][ks], b0[ks], acc[mf][0], 0, 0, 0);
        __builtin_amdgcn_s_setprio(0);
        __builtin_amdgcn_s_barrier();

        // ---- ph1: read b1(2); stage B(t+2) x2; vmcnt; MFMA a x b1 ----
        {
            int rb = wn * 32 + 16 + cb;
#pragma unroll
            for (int ks = 0; ks < 2; ks++)
                b1[ks] = *(const f16x8*)(bB + (rb << 7) +
                                         ((ks * 64 + hi * 16) ^ ((rb & 7) << 4)));
        }
        if (t + 2 < NT) { stageB(t + 2, 0); stageB(t + 2, 1); }
        if (t < NT - 2)
            asm volatile("s_waitcnt vmcnt(6)" ::: "memory");
        else if (t == NT - 2)
            asm volatile("s_waitcnt vmcnt(0)" ::: "memory");
        __builtin_amdgcn_s_barrier();
        asm volatile("s_waitcnt lgkmcnt(0)" ::: "memory");
        __builtin_amdgcn_s_setprio(1);
#pragma unroll
        for (int mf = 0; mf < 4; mf++)
#pragma unroll
            for (int ks = 0; ks < 2; ks++)
                acc[mf][1] = __builtin_amdgcn_mfma_f32_16x16x32_f16(a[mf][ks], b1[ks], acc[mf][1], 0, 0, 0);
        __builtin_amdgcn_s_setprio(0);
        __builtin_amdgcn_s_barrier();
    }

    // epilogue: direct fp32 stores
#pragma unroll
    for (int mf = 0; mf < 4; mf++)
#pragma unroll
        for (int nf = 0; nf < 2; nf++) {
            int gn = bn + wn * 32 + nf * 16 + cb;
#pragma unroll
            for (int r = 0; r < 4; r++) {
                int gm = bm + wm * 64 + mf * 16 + hi * 4 + r;
                out[(size_t)gm * H_DIM + gn] = acc[mf][nf][r];
            }
        }
}

// ---------------- attention + (fused) Wo transpose ----------------
__global__ __launch_bounds__(256) void attn_kernel(const _Float16* __restrict__ qkvb,
                                                   const float* __restrict__ bias,
                                                   const float* __restrict__ mask,
                                                   _Float16* __restrict__ aout,
                                                   const float* __restrict__ Wo,
                                                   _Float16* __restrict__ WoT) {
    __shared__ _Float16 Qs[64 * 136];
    __shared__ _Float16 Ks[64 * 136];
    __shared__ _Float16 VTs[128 * 72];
    __shared__ _Float16 Ps[64 * 72];
    __shared__ float maskv[64];

    int bid = blockIdx.x;
    int tid = threadIdx.x;

    if (bid >= NBLK * N_HEADS) {
        // ---- Wo transpose block (32x32 tile), reuses Qs as staging ----
        float* tile = (float*)Qs;
        int tb = bid - NBLK * N_HEADS;
        int tbx = (tb & 63) * 32, tby = (tb >> 6) * 32;
        int tx = tid & 31, ty = tid >> 5;  // 32 x 8
#pragma unroll
        for (int i = 0; i < 4; i++)
            tile[(ty + i * 8) * 33 + tx] = Wo[(size_t)(tby + ty + i * 8) * H_DIM + tbx + tx];
        __syncthreads();
#pragma unroll
        for (int i = 0; i < 4; i++)
            WoT[(size_t)(tbx + ty + i * 8) * H_DIM + tby + tx] =
                (_Float16)tile[tx * 33 + ty + i * 8];
        return;
    }

    int n = bid >> 4, e = bid & 15;
    int t0 = n * KBLK;
    int valid = (T_DIM - t0 < KBLK) ? (T_DIM - t0) : KBLK;

    int lane = tid & 63, wave = tid >> 6;
    const _Float16* qp = qkvb + (size_t)e * (T_DIM * DH);
    const _Float16* kp = qkvb + (size_t)(T_DIM * H_DIM) + (size_t)e * (T_DIM * DH);
    const _Float16* vp = qkvb + (size_t)2 * (T_DIM * H_DIM) + (size_t)e * (T_DIM * DH);

#pragma unroll
    for (int i = 0; i < 4; i++) {
        int c = tid + i * 256;
        int r = c >> 4, c8 = c & 15;
        uint4 z = {0u, 0u, 0u, 0u};
        uint4 vq = z, vk = z;
        if (r < valid) {
            vq = *(const uint4*)&qp[(size_t)(t0 + r) * DH + c8 * 8];
            vk = *(const uint4*)&kp[(size_t)(t0 + r) * DH + c8 * 8];
        }
        *(uint4*)&Qs[r * 136 + c8 * 8] = vq;
        *(uint4*)&Ks[r * 136 + c8 * 8] = vk;
    }
#pragma unroll
    for (int i = 0; i < 4; i++) {
        int c = tid + i * 256;
        int r = c & 63;
        int f0 = (c >> 6) * 8;
        uint4 v = {0u, 0u, 0u, 0u};
        if (r < valid) v = *(const uint4*)&vp[(size_t)(t0 + r) * DH + f0];
        _Float16 tmp[8];
        *(uint4*)tmp = v;
#pragma unroll
        for (int j = 0; j < 8; j++) VTs[(f0 + j) * 72 + r] = tmp[j];
    }
    if (tid < 64) maskv[tid] = (tid < valid) ? mask[t0 + tid] : NEGV;
    __syncthreads();

    int qr0 = wave * 16;
    int cb = lane & 15, hi = lane >> 4;

    f16x8 aq[4];
#pragma unroll
    for (int ks = 0; ks < 4; ks++)
        aq[ks] = *(const f16x8*)&Qs[(qr0 + cb) * 136 + ks * 32 + hi * 8];
    f32x4 s[4];
#pragma unroll
    for (int kt = 0; kt < 4; kt++) s[kt] = (f32x4){0.f, 0.f, 0.f, 0.f};
#pragma unroll
    for (int kt = 0; kt < 4; kt++)
#pragma unroll
        for (int ks = 0; ks < 4; ks++) {
            f16x8 bk = *(const f16x8*)&Ks[(kt * 16 + cb) * 136 + ks * 32 + hi * 8];
            s[kt] = __builtin_amdgcn_mfma_f32_16x16x32_f16(aq[ks], bk, s[kt], 0, 0, 0);
        }

#pragma unroll
    for (int r = 0; r < 4; r++) {
        int rl = qr0 + hi * 4 + r;
        int qi = t0 + rl;
        float mq = maskv[rl];
        float lg[4];
        float mx = -3.4e38f;
#pragma unroll
        for (int kt = 0; kt < 4; kt++) {
            int cl = kt * 16 + cb, ki = t0 + cl;
            float bg = (qi < T_DIM && ki < T_DIM)
                           ? bias[((size_t)e * T_DIM + qi) * T_DIM + ki] : 0.f;
            float pr = mq * maskv[cl];
            float v = s[kt][r] + bg + (pr > 0.f ? 0.f : NEGV);
            lg[kt] = v;
            mx = fmaxf(mx, v);
        }
#pragma unroll
        for (int off = 8; off; off >>= 1) mx = fmaxf(mx, __shfl_xor(mx, off));
        float sum = 0.f;
#pragma unroll
        for (int kt = 0; kt < 4; kt++) {
            float pe = __expf(lg[kt] - mx);
            lg[kt] = pe;
            sum += pe;
        }
#pragma unroll
        for (int off = 8; off; off >>= 1) sum += __shfl_xor(sum, off);
        float inv = 1.f / sum;
#pragma unroll
        for (int kt = 0; kt < 4; kt++)
            Ps[rl * 72 + kt * 16 + cb] = (_Float16)(lg[kt] * inv);
    }
    __syncthreads();

    f16x8 pa[2];
#pragma unroll
    for (int ks = 0; ks < 2; ks++)
        pa[ks] = *(const f16x8*)&Ps[(qr0 + cb) * 72 + ks * 32 + hi * 8];
#pragma unroll
    for (int ft = 0; ft < 8; ft++) {
        f32x4 o = (f32x4){0.f, 0.f, 0.f, 0.f};
#pragma unroll
        for (int ks = 0; ks < 2; ks++) {
            f16x8 bv = *(const f16x8*)&VTs[(ft * 16 + cb) * 72 + ks * 32 + hi * 8];
            o = __builtin_amdgcn_mfma_f32_16x16x32_f16(pa[ks], bv, o, 0, 0, 0);
        }
#pragma unroll
        for (int r = 0; r < 4; r++) {
            int rl = qr0 + hi * 4 + r;
            if (rl < valid)
                aout[(size_t)(t0 + rl) * H_DIM + e * DH + ft * 16 + cb] = (_Float16)o[r];
        }
    }
}

extern "C" void kernel_launch(void* const* d_in, const int* in_sizes, int n_in,
                              void* d_out, int out_size, void* d_ws, size_t ws_size,
                              hipStream_t stream) {
    const float* x    = (const float*)d_in[0];
    const float* mask = (const float*)d_in[1];
    const float* bias = (const float*)d_in[2];
    const float* Wq   = (const float*)d_in[3];
    const float* Wk   = (const float*)d_in[4];
    const float* Wv   = (const float*)d_in[5];
    const float* Wo   = (const float*)d_in[6];
    float* out = (float*)d_out;

    // ws layout (f16): xb[4M] | WT[12M] | WoT[4M] | qkv[12M] | aout[4M] = 72MB
    _Float16* xb   = (_Float16*)d_ws;
    _Float16* WT   = xb + (size_t)T_DIM * H_DIM;
    _Float16* WoT  = WT + (size_t)3 * T_DIM * H_DIM;
    _Float16* qkvb = WoT + (size_t)T_DIM * H_DIM;
    _Float16* aout = qkvb + (size_t)3 * T_DIM * H_DIM;

    prep_kernel<<<dim3(64, 64, 4), dim3(32, 8), 0, stream>>>(x, Wq, Wk, Wv, xb, WT);

    qkv_kernel<<<512, 256, 0, stream>>>(xb, WT, qkvb);

    attn_kernel<<<NBLK * N_HEADS + 4096, 256, 0, stream>>>(qkvb, bias, mask, aout, Wo, WoT);

    oproj_kernel<<<512, 256, 0, stream>>>(aout, WoT, out);
}

// Round 15
// 113.366 us; speedup vs baseline: 1.0445x; 1.0445x over previous
//
#include <hip/hip_runtime.h>
#include <hip/hip_bf16.h>

typedef _Float16 f16x8 __attribute__((ext_vector_type(8)));
typedef float f32x4 __attribute__((ext_vector_type(4)));

#define T_DIM 2048
#define H_DIM 2048
#define N_HEADS 16
#define DH 128
#define KBLK 50
#define NBLK 41
#define NEGV (-1.0e9f)
#define QSCALE 0.08838834764831845f  // 128^-0.5

__device__ __forceinline__ void gl_lds16(const void* g, void* l) {
    __builtin_amdgcn_global_load_lds(
        (const __attribute__((address_space(1))) void*)g,
        (__attribute__((address_space(3))) void*)l, 16, 0, 0);
}

// ---- prep: z<3 -> transpose Wq/Wk/Wv fp32->fp16; z==3 -> convert x fp32->fp16 ----
__global__ __launch_bounds__(256) void prep_kernel(const float* __restrict__ x,
                                                   const float* __restrict__ Wq,
                                                   const float* __restrict__ Wk,
                                                   const float* __restrict__ Wv,
                                                   _Float16* __restrict__ xb,
                                                   _Float16* __restrict__ WT) {
    __shared__ float tile[32][33];
    int z = blockIdx.z;
    int tx = threadIdx.x, ty = threadIdx.y;  // 32 x 8
    if (z == 3) {
        if (blockIdx.y >= 32) return;
        int flat = blockIdx.y * 64 + blockIdx.x;
        int i = (flat * 256 + ty * 32 + tx) * 8;
        float4 a = *(const float4*)&x[i];
        float4 b = *(const float4*)&x[i + 4];
        f16x8 o = {(_Float16)a.x, (_Float16)a.y, (_Float16)a.z, (_Float16)a.w,
                   (_Float16)b.x, (_Float16)b.y, (_Float16)b.z, (_Float16)b.w};
        *(f16x8*)&xb[i] = o;
        return;
    }
    const float* src = (z == 0) ? Wq : (z == 1) ? Wk : Wv;
    _Float16* dst = WT + (size_t)z * T_DIM * H_DIM;
    int bx = blockIdx.x * 32, by = blockIdx.y * 32;
#pragma unroll
    for (int i = 0; i < 4; i++)
        tile[ty + i * 8][tx] = src[(size_t)(by + ty + i * 8) * H_DIM + bx + tx];
    __syncthreads();
#pragma unroll
    for (int i = 0; i < 4; i++)
        dst[(size_t)(bx + ty + i * 8) * H_DIM + by + tx] = (_Float16)tile[tx][ty + i * 8];
}

// =============== QKV projection: 128x192 tile, 4-phase, 512 blocks = 2/CU ==========
__global__ __launch_bounds__(256, 2) void qkv_kernel(const _Float16* __restrict__ A,
                                                     const _Float16* __restrict__ BT,
                                                     _Float16* __restrict__ qkv) {
    const int K = 2048, NT = 32;
    __shared__ _Float16 smem[40960];  // 80KB: A dbuf 2x8192 | B dbuf 2x12288
    _Float16* sA0 = smem;
    _Float16* sA1 = smem + 8192;
    _Float16* sB0 = smem + 16384;
    _Float16* sB1 = smem + 28672;

    int tid = threadIdx.x;
    int lane = tid & 63, wave = tid >> 6;
    int wm = wave >> 1, wn = wave & 1;  // 2M x 2N, wave tile 64x96
    int cb = lane & 15, hi = lane >> 4;

    int bid = blockIdx.x;
    int by = bid >> 5, bx = bid & 31;
    int bm = by * 128, bn = bx * 192;

    f32x4 acc[4][6];
#pragma unroll
    for (int m = 0; m < 4; m++)
#pragma unroll
        for (int n = 0; n < 6; n++) acc[m][n] = (f32x4){0.f, 0.f, 0.f, 0.f};

    int rp = tid >> 3, cc = tid & 7;  // 32 rows/unit, 8 chunks/row
    int scol = ((cc ^ (rp & 7)) << 3);

    auto stageA = [&](int t, int u) {
        gl_lds16(A + (size_t)(bm + u * 32 + rp) * K + (t << 6) + scol,
                 ((t & 1) ? sA1 : sA0) + u * 2048 + tid * 8);
    };
    auto stageB = [&](int t, int u) {
        gl_lds16(BT + (size_t)(bn + u * 32 + rp) * K + (t << 6) + scol,
                 ((t & 1) ? sB1 : sB0) + u * 2048 + tid * 8);
    };

    f16x8 a[4][2], b[6][2];

    stageA(0, 0); stageA(0, 1); stageA(0, 2); stageA(0, 3);
    stageB(0, 0); stageB(0, 1); stageB(0, 2); stageB(0, 3); stageB(0, 4); stageB(0, 5);
    stageA(1, 0); stageA(1, 1); stageA(1, 2); stageA(1, 3);
    asm volatile("s_waitcnt vmcnt(4)" ::: "memory");
    __builtin_amdgcn_s_barrier();

    for (int t = 0; t < NT; t++) {
        int buf = t & 1;
        const char* bA = (const char*)(buf ? sA1 : sA0);
        const char* bB = (const char*)(buf ? sB1 : sB0);
        // ---- ph0: read a(8) + b012(6); stage B012(t+1); MFMA m01 x n012 ----
#pragma unroll
        for (int mf = 0; mf < 4; mf++) {
            int ra = wm * 64 + mf * 16 + cb;
#pragma unroll
            for (int ks = 0; ks < 2; ks++)
                a[mf][ks] = *(const f16x8*)(bA + (ra << 7) +
                                            ((ks * 64 + hi * 16) ^ ((ra & 7) << 4)));
        }
#pragma unroll
        for (int nf = 0; nf < 3; nf++) {
            int rb = wn * 96 + nf * 16 + cb;
#pragma unroll
            for (int ks = 0; ks < 2; ks++)
                b[nf][ks] = *(const f16x8*)(bB + (rb << 7) +
                                            ((ks * 64 + hi * 16) ^ ((rb & 7) << 4)));
        }
        if (t + 1 < NT) { stageB(t + 1, 0); stageB(t + 1, 1); stageB(t + 1, 2); }
        __builtin_amdgcn_s_barrier();
        asm volatile("s_waitcnt lgkmcnt(0)" ::: "memory");
        __builtin_amdgcn_s_setprio(1);
#pragma unroll
        for (int mf = 0; mf < 2; mf++)
#pragma unroll
            for (int nf = 0; nf < 3; nf++)
#pragma unroll
                for (int ks = 0; ks < 2; ks++)
                    acc[mf][nf] = __builtin_amdgcn_mfma_f32_16x16x32_f16(a[mf][ks], b[nf][ks], acc[mf][nf], 0, 0, 0);
        __builtin_amdgcn_s_setprio(0);
        __builtin_amdgcn_s_barrier();

        // ---- ph1: read b345(6); stage B345(t+1); MFMA m01 x n345 ----
#pragma unroll
        for (int nf = 3; nf < 6; nf++) {
            int rb = wn * 96 + nf * 16 + cb;
#pragma unroll
            for (int ks = 0; ks < 2; ks++)
                b[nf][ks] = *(const f16x8*)(bB + (rb << 7) +
                                            ((ks * 64 + hi * 16) ^ ((rb & 7) << 4)));
        }
        if (t + 1 < NT) { stageB(t + 1, 3); stageB(t + 1, 4); stageB(t + 1, 5); }
        __builtin_amdgcn_s_barrier();
        asm volatile("s_waitcnt lgkmcnt(0)" ::: "memory");
        __builtin_amdgcn_s_setprio(1);
#pragma unroll
        for (int mf = 0; mf < 2; mf++)
#pragma unroll
            for (int nf = 3; nf < 6; nf++)
#pragma unroll
                for (int ks = 0; ks < 2; ks++)
                    acc[mf][nf] = __builtin_amdgcn_mfma_f32_16x16x32_f16(a[mf][ks], b[nf][ks], acc[mf][nf], 0, 0, 0);
        __builtin_amdgcn_s_setprio(0);
        __builtin_amdgcn_s_barrier();

        // ---- ph2: stage A01(t+2); MFMA m23 x n012 ----
        if (t + 2 < NT) { stageA(t + 2, 0); stageA(t + 2, 1); }
        __builtin_amdgcn_s_barrier();
        __builtin_amdgcn_s_setprio(1);
#pragma unroll
        for (int mf = 2; mf < 4; mf++)
#pragma unroll
            for (int nf = 0; nf < 3; nf++)
#pragma unroll
                for (int ks = 0; ks < 2; ks++)
                    acc[mf][nf] = __builtin_amdgcn_mfma_f32_16x16x32_f16(a[mf][ks], b[nf][ks], acc[mf][nf], 0, 0, 0);
        __builtin_amdgcn_s_setprio(0);
        __builtin_amdgcn_s_barrier();

        // ---- ph3: stage A23(t+2); vmcnt confirms tile t+1; MFMA m23 x n345 ----
        if (t + 2 < NT) { stageA(t + 2, 2); stageA(t + 2, 3); }
        if (t < NT - 2)
            asm volatile("s_waitcnt vmcnt(4)" ::: "memory");
        else if (t == NT - 2)
            asm volatile("s_waitcnt vmcnt(0)" ::: "memory");
        __builtin_amdgcn_s_barrier();
        __builtin_amdgcn_s_setprio(1);
#pragma unroll
        for (int mf = 2; mf < 4; mf++)
#pragma unroll
            for (int nf = 3; nf < 6; nf++)
#pragma unroll
                for (int ks = 0; ks < 2; ks++)
                    acc[mf][nf] = __builtin_amdgcn_mfma_f32_16x16x32_f16(a[mf][ks], b[nf][ks], acc[mf][nf], 0, 0, 0);
        __builtin_amdgcn_s_setprio(0);
        __builtin_amdgcn_s_barrier();
    }

    // epilogue: single-pass LDS repack [128][200] -> coalesced uint4 scatter
#pragma unroll
    for (int mf = 0; mf < 4; mf++)
#pragma unroll
        for (int nf = 0; nf < 6; nf++) {
            int col = wn * 96 + nf * 16 + cb;
            float sc = ((bn + col) >> 11) == 0 ? QSCALE : 1.0f;
#pragma unroll
            for (int r = 0; r < 4; r++) {
                int row = wm * 64 + mf * 16 + hi * 4 + r;
                smem[row * 200 + col] = (_Float16)(acc[mf][nf][r] * sc);
            }
        }
    __builtin_amdgcn_s_barrier();
#pragma unroll
    for (int it = 0; it < 12; it++) {
        int c = it * 256 + tid;  // 3072 chunks = 128 rows x 24
        int row = c / 24, col8 = c - row * 24;
        int gm = bm + row;
        int gn = bn + col8 * 8;
        int tensor = gn >> 11;
        int ef = gn & 2047;
        int e = ef >> 7, f0 = ef & 127;
        uint4 v = *(const uint4*)&smem[row * 200 + col8 * 8];
        *(uint4*)(qkv + (size_t)tensor * (T_DIM * H_DIM) + (size_t)e * (T_DIM * DH) +
                  (size_t)gm * DH + f0) = v;
    }
}

// =============== out-proj: 128x64 tile, BK=64, triple-buffer 72KB, 2 blocks/CU ==========
__global__ __launch_bounds__(256, 2) void oproj_kernel(const _Float16* __restrict__ A,
                                                       const _Float16* __restrict__ BT,
                                                       float* __restrict__ out) {
    const int K = 2048, NT = 32;
    __shared__ _Float16 smem[36864];  // 72KB: 3 bufs x (A 8192 | B 4096) f16

    int tid = threadIdx.x;
    int lane = tid & 63, wave = tid >> 6;
    int wm = wave >> 1, wn = wave & 1;  // 2M x 2N, wave tile 64x32
    int cb = lane & 15, hi = lane >> 4;

    int bid = blockIdx.x;
    int by = bid >> 5, bx = bid & 31;
    int bm = by * 128, bn = bx * 64;

    f32x4 acc[4][2];
#pragma unroll
    for (int m = 0; m < 4; m++)
#pragma unroll
        for (int n = 0; n < 2; n++) acc[m][n] = (f32x4){0.f, 0.f, 0.f, 0.f};

    int rp = tid >> 3, cc = tid & 7;
    int scol = ((cc ^ (rp & 7)) << 3);

    auto bufp = [&](int t) { return smem + (t % 3) * 12288; };
    auto stageA = [&](int t, int u) {
        gl_lds16(A + (size_t)(bm + u * 32 + rp) * K + (t << 6) + scol,
                 bufp(t) + u * 2048 + tid * 8);
    };
    auto stageB = [&](int t, int u) {
        gl_lds16(BT + (size_t)(bn + u * 32 + rp) * K + (t << 6) + scol,
                 bufp(t) + 8192 + u * 2048 + tid * 8);
    };

    f16x8 a[4][2], b0[2], b1[2];

    stageA(0, 0); stageA(0, 1); stageA(0, 2); stageA(0, 3); stageB(0, 0); stageB(0, 1);
    stageA(1, 0); stageA(1, 1); stageA(1, 2); stageA(1, 3); stageB(1, 0); stageB(1, 1);
    asm volatile("s_waitcnt vmcnt(6)" ::: "memory");
    __builtin_amdgcn_s_barrier();

    for (int t = 0; t < NT; t++) {
        const char* bA = (const char*)bufp(t);
        const char* bB = bA + 16384;  // 8192 f16
        // ---- ph0: read a(8) + b0(2); stage A(t+2) x4; MFMA a x b0 ----
#pragma unroll
        for (int mf = 0; mf < 4; mf++) {
            int ra = wm * 64 + mf * 16 + cb;
#pragma unroll
            for (int ks = 0; ks < 2; ks++)
                a[mf][ks] = *(const f16x8*)(bA + (ra << 7) +
                                            ((ks * 64 + hi * 16) ^ ((ra & 7) << 4)));
        }
        {
            int rb = wn * 32 + cb;
#pragma unroll
            for (int ks = 0; ks < 2; ks++)
                b0[ks] = *(const f16x8*)(bB + (rb << 7) +
                                         ((ks * 64 + hi * 16) ^ ((rb & 7) << 4)));
        }
        if (t + 2 < NT) { stageA(t + 2, 0); stageA(t + 2, 1); stageA(t + 2, 2); stageA(t + 2, 3); }
        __builtin_amdgcn_s_barrier();
        asm volatile("s_waitcnt lgkmcnt(0)" ::: "memory");
        __builtin_amdgcn_s_setprio(1);
#pragma unroll
        for (int mf = 0; mf < 4; mf++)
#pragma unroll
            for (int ks = 0; ks < 2; ks++)
                acc[mf][0] = __builtin_amdgcn_mfma_f32_16x16x32_f16(a[mf][ks], b0[ks], acc[mf][0], 0, 0, 0);
        __builtin_amdgcn_s_setprio(0);
        __builtin_amdgcn_s_barrier();

        // ---- ph1: read b1(2); stage B(t+2) x2; vmcnt; MFMA a x b1 ----
        {
            int rb = wn * 32 + 16 + cb;
#pragma unroll
            for (int ks = 0; ks < 2; ks++)
                b1[ks] = *(const f16x8*)(bB + (rb << 7) +
                                         ((ks * 64 + hi * 16) ^ ((rb & 7) << 4)));
        }
        if (t + 2 < NT) { stageB(t + 2, 0); stageB(t + 2, 1); }
        if (t < NT - 2)
            asm volatile("s_waitcnt vmcnt(6)" ::: "memory");
        else if (t == NT - 2)
            asm volatile("s_waitcnt vmcnt(0)" ::: "memory");
        __builtin_amdgcn_s_barrier();
        asm volatile("s_waitcnt lgkmcnt(0)" ::: "memory");
        __builtin_amdgcn_s_setprio(1);
#pragma unroll
        for (int mf = 0; mf < 4; mf++)
#pragma unroll
            for (int ks = 0; ks < 2; ks++)
                acc[mf][1] = __builtin_amdgcn_mfma_f32_16x16x32_f16(a[mf][ks], b1[ks], acc[mf][1], 0, 0, 0);
        __builtin_amdgcn_s_setprio(0);
        __builtin_amdgcn_s_barrier();
    }

    // epilogue: direct fp32 stores
#pragma unroll
    for (int mf = 0; mf < 4; mf++)
#pragma unroll
        for (int nf = 0; nf < 2; nf++) {
            int gn = bn + wn * 32 + nf * 16 + cb;
#pragma unroll
            for (int r = 0; r < 4; r++) {
                int gm = bm + wm * 64 + mf * 16 + hi * 4 + r;
                out[(size_t)gm * H_DIM + gn] = acc[mf][nf][r];
            }
        }
}

// ---------------- attention + (fused) Wo transpose ----------------
__global__ __launch_bounds__(256) void attn_kernel(const _Float16* __restrict__ qkvb,
                                                   const float* __restrict__ bias,
                                                   const float* __restrict__ mask,
                                                   _Float16* __restrict__ aout,
                                                   const float* __restrict__ Wo,
                                                   _Float16* __restrict__ WoT) {
    __shared__ _Float16 Qs[64 * 136];
    __shared__ _Float16 Ks[64 * 136];
    __shared__ _Float16 VTs[128 * 72];
    __shared__ _Float16 Ps[64 * 72];
    __shared__ float maskv[64];

    int bid = blockIdx.x;
    int tid = threadIdx.x;

    if (bid >= NBLK * N_HEADS) {
        // ---- Wo transpose block (32x32 tile), reuses Qs as staging ----
        float* tile = (float*)Qs;
        int tb = bid - NBLK * N_HEADS;
        int tbx = (tb & 63) * 32, tby = (tb >> 6) * 32;
        int tx = tid & 31, ty = tid >> 5;  // 32 x 8
#pragma unroll
        for (int i = 0; i < 4; i++)
            tile[(ty + i * 8) * 33 + tx] = Wo[(size_t)(tby + ty + i * 8) * H_DIM + tbx + tx];
        __syncthreads();
#pragma unroll
        for (int i = 0; i < 4; i++)
            WoT[(size_t)(tbx + ty + i * 8) * H_DIM + tby + tx] =
                (_Float16)tile[tx * 33 + ty + i * 8];
        return;
    }

    int n = bid >> 4, e = bid & 15;
    int t0 = n * KBLK;
    int valid = (T_DIM - t0 < KBLK) ? (T_DIM - t0) : KBLK;

    int lane = tid & 63, wave = tid >> 6;
    const _Float16* qp = qkvb + (size_t)e * (T_DIM * DH);
    const _Float16* kp = qkvb + (size_t)(T_DIM * H_DIM) + (size_t)e * (T_DIM * DH);
    const _Float16* vp = qkvb + (size_t)2 * (T_DIM * H_DIM) + (size_t)e * (T_DIM * DH);

#pragma unroll
    for (int i = 0; i < 4; i++) {
        int c = tid + i * 256;
        int r = c >> 4, c8 = c & 15;
        uint4 z = {0u, 0u, 0u, 0u};
        uint4 vq = z, vk = z;
        if (r < valid) {
            vq = *(const uint4*)&qp[(size_t)(t0 + r) * DH + c8 * 8];
            vk = *(const uint4*)&kp[(size_t)(t0 + r) * DH + c8 * 8];
        }
        *(uint4*)&Qs[r * 136 + c8 * 8] = vq;
        *(uint4*)&Ks[r * 136 + c8 * 8] = vk;
    }
#pragma unroll
    for (int i = 0; i < 4; i++) {
        int c = tid + i * 256;
        int r = c & 63;
        int f0 = (c >> 6) * 8;
        uint4 v = {0u, 0u, 0u, 0u};
        if (r < valid) v = *(const uint4*)&vp[(size_t)(t0 + r) * DH + f0];
        _Float16 tmp[8];
        *(uint4*)tmp = v;
#pragma unroll
        for (int j = 0; j < 8; j++) VTs[(f0 + j) * 72 + r] = tmp[j];
    }
    if (tid < 64) maskv[tid] = (tid < valid) ? mask[t0 + tid] : NEGV;
    __syncthreads();

    int qr0 = wave * 16;
    int cb = lane & 15, hi = lane >> 4;

    f16x8 aq[4];
#pragma unroll
    for (int ks = 0; ks < 4; ks++)
        aq[ks] = *(const f16x8*)&Qs[(qr0 + cb) * 136 + ks * 32 + hi * 8];
    f32x4 s[4];
#pragma unroll
    for (int kt = 0; kt < 4; kt++) s[kt] = (f32x4){0.f, 0.f, 0.f, 0.f};
#pragma unroll
    for (int kt = 0; kt < 4; kt++)
#pragma unroll
        for (int ks = 0; ks < 4; ks++) {
            f16x8 bk = *(const f16x8*)&Ks[(kt * 16 + cb) * 136 + ks * 32 + hi * 8];
            s[kt] = __builtin_amdgcn_mfma_f32_16x16x32_f16(aq[ks], bk, s[kt], 0, 0, 0);
        }

#pragma unroll
    for (int r = 0; r < 4; r++) {
        int rl = qr0 + hi * 4 + r;
        int qi = t0 + rl;
        float mq = maskv[rl];
        float lg[4];
        float mx = -3.4e38f;
#pragma unroll
        for (int kt = 0; kt < 4; kt++) {
            int cl = kt * 16 + cb, ki = t0 + cl;
            float bg = (qi < T_DIM && ki < T_DIM)
                           ? bias[((size_t)e * T_DIM + qi) * T_DIM + ki] : 0.f;
            float pr = mq * maskv[cl];
            float v = s[kt][r] + bg + (pr > 0.f ? 0.f : NEGV);
            lg[kt] = v;
            mx = fmaxf(mx, v);
        }
#pragma unroll
        for (int off = 8; off; off >>= 1) mx = fmaxf(mx, __shfl_xor(mx, off));
        float sum = 0.f;
#pragma unroll
        for (int kt = 0; kt < 4; kt++) {
            float pe = __expf(lg[kt] - mx);
            lg[kt] = pe;
            sum += pe;
        }
#pragma unroll
        for (int off = 8; off; off >>= 1) sum += __shfl_xor(sum, off);
        float inv = 1.f / sum;
#pragma unroll
        for (int kt = 0; kt < 4; kt++)
            Ps[rl * 72 + kt * 16 + cb] = (_Float16)(lg[kt] * inv);
    }
    __syncthreads();

    f16x8 pa[2];
#pragma unroll
    for (int ks = 0; ks < 2; ks++)
        pa[ks] = *(const f16x8*)&Ps[(qr0 + cb) * 72 + ks * 32 + hi * 8];
#pragma unroll
    for (int ft = 0; ft < 8; ft++) {
        f32x4 o = (f32x4){0.f, 0.f, 0.f, 0.f};
#pragma unroll
        for (int ks = 0; ks < 2; ks++) {
            f16x8 bv = *(const f16x8*)&VTs[(ft * 16 + cb) * 72 + ks * 32 + hi * 8];
            o = __builtin_amdgcn_mfma_f32_16x16x32_f16(pa[ks], bv, o, 0, 0, 0);
        }
#pragma unroll
        for (int r = 0; r < 4; r++) {
            int rl = qr0 + hi * 4 + r;
            if (rl < valid)
                aout[(size_t)(t0 + rl) * H_DIM + e * DH + ft * 16 + cb] = (_Float16)o[r];
        }
    }
}

extern "C" void kernel_launch(void* const* d_in, const int* in_sizes, int n_in,
                              void* d_out, int out_size, void* d_ws, size_t ws_size,
                              hipStream_t stream) {
    const float* x    = (const float*)d_in[0];
    const float* mask = (const float*)d_in[1];
    const float* bias = (const float*)d_in[2];
    const float* Wq   = (const float*)d_in[3];
    const float* Wk   = (const float*)d_in[4];
    const float* Wv   = (const float*)d_in[5];
    const float* Wo   = (const float*)d_in[6];
    float* out = (float*)d_out;

    // ws layout (f16): xb[4M] | WT[12M] | WoT[4M] | qkv[12M] | aout[4M] = 72MB
    _Float16* xb   = (_Float16*)d_ws;
    _Float16* WT   = xb + (size_t)T_DIM * H_DIM;
    _Float16* WoT  = WT + (size_t)3 * T_DIM * H_DIM;
    _Float16* qkvb = WoT + (size_t)T_DIM * H_DIM;
    _Float16* aout = qkvb + (size_t)3 * T_DIM * H_DIM;

    prep_kernel<<<dim3(64, 64, 4), dim3(32, 8), 0, stream>>>(x, Wq, Wk, Wv, xb, WT);

    qkv_kernel<<<512, 256, 0, stream>>>(xb, WT, qkvb);

    attn_kernel<<<NBLK * N_HEADS + 4096, 256, 0, stream>>>(qkvb, bias, mask, aout, Wo, WoT);

    oproj_kernel<<<512, 256, 0, stream>>>(aout, WoT, out);
}